// Round 14
// baseline (817.951 us; speedup 1.0000x reference)
//
#include <hip/hip_runtime.h>
#include <stdint.h>

typedef unsigned short u16;
typedef unsigned int   u32;
typedef __bf16 bf16x8 __attribute__((ext_vector_type(8)));
typedef float  f32x4  __attribute__((ext_vector_type(4)));
typedef u16    u16x8  __attribute__((ext_vector_type(8)));
typedef u16    u16x4  __attribute__((ext_vector_type(4)));

// Problem dims
#define NB    4
#define NS    4096
#define NHID  2048
#define NHEAD 16
#define HDIM  128
#define NKT   32    // K-tiles of 64 (K=2048)

__device__ __forceinline__ u16 f2bf(float f) {
  u32 u = __builtin_bit_cast(u32, f);
  u = (u + 0x7fffu + ((u >> 16) & 1u)) >> 16;
  return (u16)u;
}
__device__ __forceinline__ float bf2f(u16 h) {
  return __builtin_bit_cast(float, ((u32)h) << 16);
}

__device__ __forceinline__ void async_copy16(u16* lds_dst, const u16* g_src) {
  __builtin_amdgcn_global_load_lds(
      (__attribute__((address_space(1))) u32*)(const_cast<u16*>(g_src)),
      (__attribute__((address_space(3))) u32*)(lds_dst),
      16, 0, 0);
}

#define SBAR()  __builtin_amdgcn_sched_barrier(0)
#define BARRIER() do { SBAR(); __builtin_amdgcn_s_barrier(); SBAR(); } while (0)
#define LGKM0() asm volatile("s_waitcnt lgkmcnt(0)" ::: "memory")
#define VM0()   asm volatile("s_waitcnt vmcnt(0)"   ::: "memory")

// ===========================================================================
// r14 core: m201 PHASE RHYTHM on the r12-proven ledger.
// 256x256 tile, BK=64, 8 waves (2M x 4N). LDS 2 dbuf x 64KB = 128KB;
// regions per buffer: A-kg0 @0, A-kg1 @8192, B-kg0 @16384, B-kg1 @24576,
// each [row:256][32 elems] (r12 layout, deterministically PASSED).
//
// Phase Q (quadrant: Q0=mq0/kg0, Q1=mq1/kg0, Q2=mq0/kg1, Q3=mq1/kg1):
//   { ds_reads for THIS phase's MFMA (data certified, see ledger);
//     stage 1 region of tile t+1;  [vmcnt(4) at Q1 and Q3];
//     s_barrier;  lgkmcnt(0);  setprio(1) 16 MFMA setprio(0);  s_barrier }
// The read-issue happens before the barrier (LDS unit drains during the
// barrier wait) and the double barrier phase-offsets the waves — the m201
// mechanism that breaks the per-wave LDS->MFMA serialization diagnosed in
// r13 (LDS 2304 + MFMA 2483 = measured 5094 cyc/tile/CU, a clean sum).
//
// Cert ledger (per-wave FIFO, 2 loads/stage; re-audited):
//   steady state, enter t.Q0 with 4 in flight {A-kg1(t), B-kg1(t)}:
//   Q0 stages A-kg0(t+1)->6; Q1 stages B-kg0(t+1)->8, vmcnt(4) retires
//   {A-kg1(t), B-kg1(t)} = exactly what t.Q2/Q3's reads need (they read
//   after Q1's 2nd barrier);  Q2 stages A-kg1(t+1)->6; Q3 stages
//   B-kg1(t+1)->8, vmcnt(4) retires {A-kg0(t+1), B-kg0(t+1)} = what
//   t+1.Q0/Q1 read. Counted waits on ~1-tile-old loads; never drains.
//   t=0: prologue DRAINS tile 0 (vmcnt(0), order-independent — r12 fix);
//   Q1's vmcnt(4) is then a no-op (4 in flight).  Peel (t=NKT-1): enter
//   with 4 {A-kg1,B-kg1}; no staging; Q1 uses vmcnt(0); Q3 no wait.
// WAR: phase Q's reads drain at Q's lgkmcnt(0); any region's overwrite
// (next tile's stage) is >=2 barriers later.
// ===========================================================================
__device__ __forceinline__ void stage10(u16* dst, const u16* src,
                                        int kt, int kg, int tid)
{
#pragma unroll
  for (int i = 0; i < 2; ++i) {
    const int U = (i << 9) + tid;            // [0,1024) 16B units, 4 per row
    const int r = U >> 2, u = U & 3;
    const int col = (kt << 6) + (kg << 5) + ((u ^ ((r >> 1) & 3)) << 3);
    async_copy16(dst + U * 8, src + (size_t)r * 2048 + col);
  }
}

__device__ __forceinline__ void rdA(bf16x8 (&d)[4], const u16* base, int mq)
{
#pragma unroll
  for (int m = 0; m < 4; ++m)
    d[m] = *(const bf16x8*)(base + mq * 2048 + m * 512);
}

__device__ __forceinline__ void rdB(bf16x8 (&d)[4], const u16* base)
{
#pragma unroll
  for (int n = 0; n < 4; ++n)
    d[n] = *(const bf16x8*)(base + n * 512);
}

template<bool SWAP>
__device__ __forceinline__ void mmcl(f32x4 (&acc)[8][4], int mq,
                                     const bf16x8 (&a)[4], const bf16x8 (&b)[4])
{
  __builtin_amdgcn_s_setprio(1);
#pragma unroll
  for (int mm = 0; mm < 4; ++mm)
#pragma unroll
    for (int n = 0; n < 4; ++n) {
      if (SWAP)
        acc[mq * 4 + mm][n] = __builtin_amdgcn_mfma_f32_16x16x32_bf16(b[n], a[mm], acc[mq * 4 + mm][n], 0, 0, 0);
      else
        acc[mq * 4 + mm][n] = __builtin_amdgcn_mfma_f32_16x16x32_bf16(a[mm], b[n], acc[mq * 4 + mm][n], 0, 0, 0);
    }
  __builtin_amdgcn_s_setprio(0);
}

// one m201-rhythm phase. VMW: -1 none, 4 counted, 0 drain.
template<int Q, int VMW, bool STG, bool SWAP>
__device__ __forceinline__ void phase14(const u16* Lc, u16* Ln,
                                        const u16* __restrict__ A,
                                        const u16* __restrict__ B, int ktn,
                                        bf16x8 (&aR)[4], bf16x8 (&bR)[4],
                                        f32x4 (&acc)[8][4],
                                        int tid, int arow, int brow)
{
  // reads at phase top (certification per ledger above)
  if (Q == 0) { rdB(bR, Lc + 16384 + brow); rdA(aR, Lc + arow, 0); }
  if (Q == 1) { rdA(aR, Lc + arow, 1); }
  if (Q == 2) { rdB(bR, Lc + 24576 + brow); rdA(aR, Lc + 8192 + arow, 0); }
  if (Q == 3) { rdA(aR, Lc + 8192 + arow, 1); }
  if (STG) {
    if (Q == 0) stage10(Ln,         A, ktn, 0, tid);
    if (Q == 1) stage10(Ln + 16384, B, ktn, 0, tid);
    if (Q == 2) stage10(Ln + 8192,  A, ktn, 1, tid);
    if (Q == 3) stage10(Ln + 24576, B, ktn, 1, tid);
  }
  if constexpr (VMW >= 0) {
    asm volatile("s_waitcnt vmcnt(%0)" :: "n"(VMW) : "memory");
  }
  BARRIER();            // 1st barrier: publish stage targets / phase split
  LGKM0();              // this wave's phase-top reads have landed
  SBAR();               // rule #18: don't hoist MFMA above the wait
  mmcl<SWAP>(acc, (Q & 1), aR, bR);
  BARRIER();            // 2nd barrier: close the phase
}

template<bool SWAP>
__device__ __forceinline__ void gemm14(const u16* __restrict__ A,
                                       const u16* __restrict__ B,
                                       f32x4 (&acc)[8][4], u16* L)
{
  const int tid = threadIdx.x, lane = tid & 63, w = tid >> 6;
  const int wr = w >> 2, wc = w & 3, lg = lane >> 4, lr = lane & 15;
  const int ggx = ((lg ^ ((lr >> 1) & 3)) << 3);
  const int arow = wr * 4096 + lr * 32 + ggx;   // elem offset in A region
  const int brow = wc * 2048 + lr * 32 + ggx;   // elem offset in B region

#pragma unroll
  for (int m = 0; m < 8; ++m)
#pragma unroll
    for (int n = 0; n < 4; ++n) acc[m][n] = f32x4{0.f, 0.f, 0.f, 0.f};

  // prologue: tile 0 -> buf0; DRAIN (order-independent cert, r12 lesson)
  stage10(L,         A, 0, 0, tid);   // A-kg0
  stage10(L + 16384, B, 0, 0, tid);   // B-kg0
  stage10(L + 8192,  A, 0, 1, tid);   // A-kg1
  stage10(L + 24576, B, 0, 1, tid);   // B-kg1
  VM0();
  BARRIER();

  bf16x8 aR[4], bR[4];
#pragma unroll 1
  for (int t = 0; t < NKT - 1; ++t) {
    const u16* Lc = L + ((t & 1) << 15);
    u16* Ln = L + (((t + 1) & 1) << 15);
    phase14<0, -1, true, SWAP>(Lc, Ln, A, B, t + 1, aR, bR, acc, tid, arow, brow);
    phase14<1,  4, true, SWAP>(Lc, Ln, A, B, t + 1, aR, bR, acc, tid, arow, brow);
    phase14<2, -1, true, SWAP>(Lc, Ln, A, B, t + 1, aR, bR, acc, tid, arow, brow);
    phase14<3,  4, true, SWAP>(Lc, Ln, A, B, t + 1, aR, bR, acc, tid, arow, brow);
  }
  {  // peeled last tile: no staging; Q1 drains the 4 stale kg1 loads
    const u16* Lc = L + (((NKT - 1) & 1) << 15);
    phase14<0, -1, false, SWAP>(Lc, nullptr, A, B, 0, aR, bR, acc, tid, arow, brow);
    phase14<1,  0, false, SWAP>(Lc, nullptr, A, B, 0, aR, bR, acc, tid, arow, brow);
    phase14<2, -1, false, SWAP>(Lc, nullptr, A, B, 0, aR, bR, acc, tid, arow, brow);
    phase14<3, -1, false, SWAP>(Lc, nullptr, A, B, 0, aR, bR, acc, tid, arow, brow);
  }
}

// ---------------------------------------------------------------------------
// GEMM1: qkvg = x_bf16 [16384,2048] @ WTcat^T [8192,2048], +bias.
// q,g (swapped-C) -> [s][2048], 8B stores (sigmoid on g);
// k,v (normal-C)  -> directly transposed [bh][d][s], 8B stores.
// grid: 2048 blocks (64 mt x 32 nt), 16x16 supergroups for L2.
// ---------------------------------------------------------------------------
__global__ __launch_bounds__(512, 2) void k_gemm_qkvg(
    const u16* __restrict__ xb, const u16* __restrict__ WT,
    const float* __restrict__ bias,
    u16* __restrict__ q, u16* __restrict__ kT, u16* __restrict__ vT,
    u16* __restrict__ g)
{
  __shared__ u16 L[65536];
  const int bid = blockIdx.x;
  const int grp = bid >> 8, r = bid & 255;
  const int mt = ((grp & 3) << 4) + (r & 15);
  const int nt = ((grp >> 2) << 4) + (r >> 4);
  const size_t bm0 = (size_t)mt << 8;
  const int    bn0 = nt << 8;
  const int nblk = bn0 >> 11;          // 0=q 1=k 2=v 3=g
  const int ocol0 = bn0 & 2047;

  const int tid = threadIdx.x, lane = tid & 63, w = tid >> 6;
  const int wr = w >> 2, wc = w & 3, lg = lane >> 4, lr = lane & 15;

  f32x4 acc[8][4];
  const u16* Ap = xb + bm0 * NHID;
  const u16* Bp = WT + (size_t)bn0 * NHID;

  if (nblk == 0 || nblk == 3) {
    gemm14<true>(Ap, Bp, acc, L);
    u16* outp = (nblk == 0) ? q : g;
    const bool sig = (nblk == 3);
#pragma unroll
    for (int m = 0; m < 8; ++m) {
      const size_t row = bm0 + (wr << 7) + (m << 4) + lr;
#pragma unroll
      for (int n = 0; n < 4; ++n) {
        const int colb = (wc << 6) + (n << 4) + (lg << 2);
        const float* bp = bias + bn0 + colb;
        u16x4 o;
#pragma unroll
        for (int j = 0; j < 4; ++j) {
          float val = acc[m][n][j] + bp[j];
          if (sig) val = 1.f / (1.f + __expf(-val));
          o[j] = f2bf(val);
        }
        *(u16x4*)(outp + row * NHID + ocol0 + colb) = o;
      }
    }
  } else {
    gemm14<false>(Ap, Bp, acc, L);
    u16* outp = (nblk == 1) ? kT : vT;
    const int b = (int)(bm0 >> 12);
    const int srow0 = (int)(bm0 & 4095) + (wr << 7) + (lg << 2);
#pragma unroll
    for (int m = 0; m < 8; ++m) {
      const int srow = srow0 + (m << 4);
#pragma unroll
      for (int n = 0; n < 4; ++n) {
        const int cg = ocol0 + (wc << 6) + (n << 4) + lr;  // col in [0,2048)
        const int h = cg >> 7, d = cg & 127;
        const float bia = bias[bn0 + (wc << 6) + (n << 4) + lr];
        u16x4 o;
#pragma unroll
        for (int j = 0; j < 4; ++j) o[j] = f2bf(acc[m][n][j] + bia);
        *(u16x4*)(outp + (((size_t)(b * NHEAD + h) * HDIM + d) << 12) + srow) = o;
      }
    }
  }
}

// ---------------------------------------------------------------------------
// out = attn @ WoT^T + bo (fp32, swapped-C -> float4 stores)
// grid: 512 blocks (64 mt x 8 nt), 16x8 supergroups
// ---------------------------------------------------------------------------
__global__ __launch_bounds__(512, 2) void k_gemm_out(
    const u16* __restrict__ attn, const u16* __restrict__ WoT,
    const float* __restrict__ bo, float* __restrict__ out)
{
  __shared__ u16 L[65536];
  const int bid = blockIdx.x;
  const int grp = bid >> 7, rr = bid & 127;
  const int mt = (grp << 4) + (rr & 15);
  const int nt = rr >> 4;
  const size_t bm0 = (size_t)mt << 8;
  const int    bn0 = nt << 8;

  const int tid = threadIdx.x, lane = tid & 63, w = tid >> 6;
  const int wr = w >> 2, wc = w & 3, lg = lane >> 4, lr = lane & 15;

  f32x4 acc[8][4];
  gemm14<true>(attn + bm0 * NHID, WoT + (size_t)bn0 * NHID, acc, L);

#pragma unroll
  for (int m = 0; m < 8; ++m) {
    const size_t row = bm0 + (wr << 7) + (m << 4) + lr;
#pragma unroll
    for (int n = 0; n < 4; ++n) {
      const int colb = bn0 + (wc << 6) + (n << 4) + (lg << 2);
      f32x4 o;
#pragma unroll
      for (int j = 0; j < 4; ++j) o[j] = acc[m][n][j] + bo[colb + j];
      *(f32x4*)(out + row * NHID + colb) = o;
    }
  }
}

// ===========================================================================
// Small 128x128 GEMM core (round-0 verified) for the tiny per-head GEMMs
// ===========================================================================
__device__ __forceinline__ void gemm_core(const u16* A, int lda,
                                          const u16* B, int ldb,
                                          int K, f32x4 acc[4][4],
                                          u16* As, u16* Bs)
{
  const int tid  = threadIdx.x;
  const int lane = tid & 63;
  const int w    = tid >> 6;
  const int wr   = (w >> 1) << 6;
  const int wc   = (w & 1) << 6;
  const int lg   = lane >> 4;
  const int lr   = lane & 15;

#pragma unroll
  for (int m = 0; m < 4; ++m)
#pragma unroll
    for (int n = 0; n < 4; ++n) acc[m][n] = f32x4{0.f, 0.f, 0.f, 0.f};

  for (int k0 = 0; k0 < K; k0 += 32) {
#pragma unroll
    for (int issue = 0; issue < 2; ++issue) {
      int c   = issue * 256 + tid;
      int row = c >> 2, cc = (c & 3) << 3;
      async_copy16(As + c * 8, A + (size_t)row * lda + k0 + cc);
    }
#pragma unroll
    for (int issue = 0; issue < 2; ++issue) {
      int c   = issue * 256 + tid;
      int row = c >> 2, cc = (c & 3) << 3;
      async_copy16(Bs + c * 8, B + (size_t)row * ldb + k0 + cc);
    }
    __syncthreads();

    bf16x8 af[4], bv[4];
#pragma unroll
    for (int m = 0; m < 4; ++m)
      af[m] = *(const bf16x8*)(As + ((wr + m * 16 + lr) << 5) + (lg << 3));
#pragma unroll
    for (int n = 0; n < 4; ++n)
      bv[n] = *(const bf16x8*)(Bs + ((wc + n * 16 + lr) << 5) + (lg << 3));

#pragma unroll
    for (int m = 0; m < 4; ++m)
#pragma unroll
      for (int n = 0; n < 4; ++n)
        acc[m][n] = __builtin_amdgcn_mfma_f32_16x16x32_bf16(af[m], bv[n], acc[m][n], 0, 0, 0);

    __syncthreads();
  }
}

// ---------------------------------------------------------------------------
// kv partial: C[e][d] = sum_{s chunk} vT[e][s]*kT[d][s]; grid (64 bh, 8 split)
// ---------------------------------------------------------------------------
__global__ __launch_bounds__(256) void k_gemm_kv(
    const u16* __restrict__ vT, const u16* __restrict__ kT, float* __restrict__ part)
{
  __shared__ u16 As[128 * 32];
  __shared__ u16 Bs[128 * 32];
  const int bh = blockIdx.x, sp = blockIdx.y;
  const u16* A  = vT + (size_t)bh * (HDIM * NS) + sp * 512;
  const u16* Bt = kT + (size_t)bh * (HDIM * NS) + sp * 512;
  f32x4 acc[4][4];
  gemm_core(A, NS, Bt, NS, 512, acc, As, Bs);

  float* outp = part + ((size_t)sp * 64 + bh) * 16384;
  const int tid = threadIdx.x, lane = tid & 63, w = tid >> 6;
  const int wr = (w >> 1) << 6, wc = (w & 1) << 6, lg = lane >> 4, lr = lane & 15;
#pragma unroll
  for (int m = 0; m < 4; ++m)
#pragma unroll
    for (int n = 0; n < 4; ++n) {
      const int col = wc + n * 16 + lr;
#pragma unroll
      for (int j = 0; j < 4; ++j) {
        const int row = wr + m * 16 + lg * 4 + j;
        outp[row * 128 + col] = acc[m][n][j];
      }
    }
}

// ---------------------------------------------------------------------------
// attn = (q @ kv) * g ; grid (32 stiles, 64 bh)
// ---------------------------------------------------------------------------
__global__ __launch_bounds__(256) void k_gemm_attn(
    const u16* __restrict__ q, const u16* __restrict__ kvT,
    const u16* __restrict__ g, u16* __restrict__ attn)
{
  __shared__ u16 As[128 * 32];
  __shared__ u16 Bs[128 * 32];
  const int st = blockIdx.x, bh = blockIdx.y;
  const int b = bh >> 4, h = bh & 15;
  const size_t bs0 = (size_t)b * NS + st * 128;
  f32x4 acc[4][4];
  gemm_core(q + bs0 * NHID + h * HDIM, NHID, kvT + (size_t)bh * 16384, HDIM, HDIM, acc, As, Bs);

  const int tid = threadIdx.x, lane = tid & 63, w = tid >> 6;
  const int wr = (w >> 1) << 6, wc = (w & 1) << 6, lg = lane >> 4, lr = lane & 15;
#pragma unroll
  for (int m = 0; m < 4; ++m)
#pragma unroll
    for (int n = 0; n < 4; ++n) {
      const int col = wc + n * 16 + lr;
#pragma unroll
      for (int j = 0; j < 4; ++j) {
        const int row = wr + m * 16 + lg * 4 + j;
        const size_t idx = (bs0 + row) * NHID + h * HDIM + col;
        attn[idx] = f2bf(acc[m][n][j] * bf2f(g[idx]));
      }
    }
}

// ---------------------------------------------------------------------------
// x fp32 -> bf16
// ---------------------------------------------------------------------------
__global__ __launch_bounds__(256) void k_cvt_x(const float* __restrict__ x, u16* __restrict__ xb)
{
  const size_t i = (size_t)blockIdx.x * 256 + threadIdx.x;
  const float4* xf = (const float4*)x;
  float4 a = xf[2 * i];
  float4 b = xf[2 * i + 1];
  u16x8 o;
  o[0] = f2bf(a.x); o[1] = f2bf(a.y); o[2] = f2bf(a.z); o[3] = f2bf(a.w);
  o[4] = f2bf(b.x); o[5] = f2bf(b.y); o[6] = f2bf(b.z); o[7] = f2bf(b.w);
  ((u16x8*)xb)[i] = o;
}

// ---------------------------------------------------------------------------
// All 5 weights [2048][2048] fp32 -> WT bf16 transposed, one launch.
// grid (32 ktiles, 32 ntiles, 5 weights)
// ---------------------------------------------------------------------------
__global__ __launch_bounds__(256) void k_cvt_w_t5(
    const float* __restrict__ Wq, const float* __restrict__ Wk,
    const float* __restrict__ Wv, const float* __restrict__ Wg,
    const float* __restrict__ Wo,
    u16* __restrict__ WT, u16* __restrict__ WoT)
{
  __shared__ u16 t[64][72];
  const int kt = blockIdx.x, nt = blockIdx.y, z = blockIdx.z;
  const float* W = (z == 0) ? Wq : (z == 1) ? Wk : (z == 2) ? Wv
                 : (z == 3) ? Wg : Wo;
  u16* dst = (z == 4) ? WoT : (WT + (size_t)z * 2048 * 2048);
  const int tid = threadIdx.x;
#pragma unroll
  for (int pass = 0; pass < 4; ++pass) {
    int c = pass * 256 + tid;
    int r = c >> 4, cc = (c & 15) << 2;
    float4 vv = *(const float4*)(W + (size_t)(kt * 64 + r) * 2048 + nt * 64 + cc);
    u16x4 o;
    o[0] = f2bf(vv.x); o[1] = f2bf(vv.y); o[2] = f2bf(vv.z); o[3] = f2bf(vv.w);
    *(u16x4*)&t[r][cc] = o;
  }
  __syncthreads();
#pragma unroll
  for (int pass = 0; pass < 2; ++pass) {
    int c = pass * 256 + tid;
    int rn = c >> 3, cs = (c & 7) << 3;
    u16x8 o;
#pragma unroll
    for (int j = 0; j < 8; ++j) o[j] = t[cs + j][rn];
    *(u16x8*)(dst + (size_t)(nt * 64 + rn) * 2048 + kt * 64 + cs) = o;
  }
}

// ---------------------------------------------------------------------------
__global__ __launch_bounds__(256) void k_bias_cat(
    const float* __restrict__ bq, const float* __restrict__ bk,
    const float* __restrict__ bv, const float* __restrict__ bg, float* __restrict__ o)
{
  const int i = blockIdx.x * 256 + threadIdx.x;  // 8192
  const int blk = i >> 11;
  const float* s = (blk == 0) ? bq : (blk == 1) ? bk : (blk == 2) ? bv : bg;
  o[i] = s[i & 2047];
}

__global__ __launch_bounds__(256) void k_kv_reduce(const float* __restrict__ part, u16* __restrict__ kvT)
{
  const int i = blockIdx.x * 256 + threadIdx.x;  // 1,048,576
  float s = 0.f;
#pragma unroll
  for (int sp = 0; sp < 8; ++sp) s += part[(size_t)sp * 1048576 + i];
  kvT[i] = f2bf(s);
}

// ---------------------------------------------------------------------------
extern "C" void kernel_launch(void* const* d_in, const int* in_sizes, int n_in,
                              void* d_out, int out_size, void* d_ws, size_t ws_size,
                              hipStream_t stream)
{
  const float* x  = (const float*)d_in[0];
  const float* Wq = (const float*)d_in[1];
  const float* bq = (const float*)d_in[2];
  const float* Wk = (const float*)d_in[3];
  const float* bk = (const float*)d_in[4];
  const float* Wv = (const float*)d_in[5];
  const float* bv = (const float*)d_in[6];
  const float* Wg = (const float*)d_in[7];
  const float* bg = (const float*)d_in[8];
  const float* Wo = (const float*)d_in[9];
  const float* bo = (const float*)d_in[10];
  float* out = (float*)d_out;

  char* ws = (char*)d_ws;
  u16*   xb   = (u16*)(ws + 0x00000000ULL);  // 64MB
  u16*   WT   = (u16*)(ws + 0x04000000ULL);  // 32MB  [Wq|Wk|Wv|Wg]^T bf16
  u16*   WoT  = (u16*)(ws + 0x06000000ULL);  // 8MB
  float* bias = (float*)(ws + 0x06800000ULL);// 32KB
  u16*   q    = (u16*)(ws + 0x06900000ULL);  // 64MB
  u16*   kT   = (u16*)(ws + 0x0A900000ULL);  // 64MB  [bh][d][s]
  u16*   vT   = (u16*)(ws + 0x0E900000ULL);  // 64MB  [bh][d][s]
  u16*   gg   = (u16*)(ws + 0x12900000ULL);  // 64MB
  u16*   kvT  = (u16*)(ws + 0x16900000ULL);  // 2MB
  // aliases (producer/consumer disjoint across sequential launches)
  float* part = (float*)WT;   // WT dead after qkvg (exactly 32MB)
  u16*   attn = xb;           // xb dead after qkvg

  if (ws_size < 0x16B00000ULL) return;

  k_cvt_x<<<16384, 256, 0, stream>>>(x, xb);
  k_cvt_w_t5<<<dim3(32, 32, 5), 256, 0, stream>>>(Wq, Wk, Wv, Wg, Wo, WT, WoT);
  k_bias_cat<<<32, 256, 0, stream>>>(bq, bk, bv, bg, bias);

  k_gemm_qkvg<<<2048, 512, 0, stream>>>(xb, WT, bias, q, kT, vT, gg);

  k_gemm_kv<<<dim3(64, 8), 256, 0, stream>>>(vT, kT, part);
  k_kv_reduce<<<4096, 256, 0, stream>>>(part, kvT);

  k_gemm_attn<<<dim3(32, 64), 256, 0, stream>>>(q, kvT, gg, attn);
  k_gemm_out<<<512, 512, 0, stream>>>(attn, WoT, bo, out);
}

// Round 15
// 776.701 us; speedup vs baseline: 1.0531x; 1.0531x over previous
//
#include <hip/hip_runtime.h>
#include <stdint.h>

typedef unsigned short u16;
typedef unsigned int   u32;
typedef __bf16 bf16x8 __attribute__((ext_vector_type(8)));
typedef float  f32x4  __attribute__((ext_vector_type(4)));
typedef u16    u16x8  __attribute__((ext_vector_type(8)));
typedef u16    u16x4  __attribute__((ext_vector_type(4)));

// Problem dims
#define NB    4
#define NS    4096
#define NHID  2048
#define NHEAD 16
#define HDIM  128
#define NKT   32    // K-tiles of 64 (K=2048)

__device__ __forceinline__ u16 f2bf(float f) {
  u32 u = __builtin_bit_cast(u32, f);
  u = (u + 0x7fffu + ((u >> 16) & 1u)) >> 16;
  return (u16)u;
}
__device__ __forceinline__ float bf2f(u16 h) {
  return __builtin_bit_cast(float, ((u32)h) << 16);
}

__device__ __forceinline__ void async_copy16(u16* lds_dst, const u16* g_src) {
  __builtin_amdgcn_global_load_lds(
      (__attribute__((address_space(1))) u32*)(const_cast<u16*>(g_src)),
      (__attribute__((address_space(3))) u32*)(lds_dst),
      16, 0, 0);
}

#define SBAR()  __builtin_amdgcn_sched_barrier(0)
#define BARRIER() do { SBAR(); __builtin_amdgcn_s_barrier(); SBAR(); } while (0)
#define LGKM0() asm volatile("s_waitcnt lgkmcnt(0)" ::: "memory")
#define VM0()   asm volatile("s_waitcnt vmcnt(0)"   ::: "memory")

// ===========================================================================
// r13 core (SESSION BEST, verified 543us/45.6% MfmaUtil, total 777us):
// r9 data paths + 1 barrier per K-tile.
//
// Ledger (audited): all certification flows through the single per-tile
// sync point {lgkmcnt(0); vmcnt(0); s_barrier}:
//  - Lc(t)=L[t&1] data certified at tile t-1's sync.            [RAW ok]
//  - Stage into L[(t+1)&1] at tile t's top: last reads of that buffer
//    completed before sync(t-1)'s lgkmcnt(0); stage issued after. [WAR ok]
//  - Next-tile prefetch completes before sync(t+1); overwrite at t+2's
//    top, after sync(t+1).                                       [WAR ok]
//  - vmcnt(0) is per-wave; each wave's 8 stage loads are a full tile body
//    (~1000+ cyc) old -> near-free, order-independent (r12 lesson).
//
// LDS: 2 buffers x {A[2 half][128][64], B[2 half][128][64]} = 128 KB.
// Swizzle (verified conflicts=0): 16B-unit u ^= (row&7); staged via
// inverse-permuted GLOBAL source, linear LDS dest (m173).
// ===========================================================================
__device__ __forceinline__ void stage9(u16* dst, const u16* src, int kt, int tid)
{
#pragma unroll
  for (int i = 0; i < 2; ++i) {
    const int U = (i << 9) + tid;            // [0,1024) 16B units, 8 per row
    const int r = U >> 3, u = U & 7;
    const int col = (kt << 6) + ((u ^ (r & 7)) << 3);  // inverse-swizzled src
    async_copy16(dst + U * 8, src + (size_t)r * 2048 + col);
  }
}

__device__ __forceinline__ void rd_a(bf16x8 (&d)[4], const u16* base,
                                     int kg, int mq, int lg, int lr)
{
#pragma unroll
  for (int m = 0; m < 4; ++m) {
    const int row = (mq << 6) + (m << 4) + lr;
    const int c = ((kg << 2) | lg) ^ (row & 7);
    d[m] = *(const bf16x8*)(base + row * 64 + (c << 3));
  }
}

__device__ __forceinline__ void rd_b(bf16x8 (&d)[4], const u16* base,
                                     int kg, int lg, int lr)
{
#pragma unroll
  for (int n = 0; n < 4; ++n) {
    const int row = (n << 4) + lr;           // base folds (wc&1)*64 rows
    const int c = ((kg << 2) | lg) ^ (row & 7);
    d[n] = *(const bf16x8*)(base + row * 64 + (c << 3));
  }
}

template<bool SWAP>
__device__ __forceinline__ void mmcl(f32x4 (&acc)[8][4], int mq,
                                     const bf16x8 (&a)[4], const bf16x8 (&b)[4])
{
  __builtin_amdgcn_s_setprio(1);
#pragma unroll
  for (int mm = 0; mm < 4; ++mm)
#pragma unroll
    for (int n = 0; n < 4; ++n) {
      if (SWAP)
        acc[mq * 4 + mm][n] = __builtin_amdgcn_mfma_f32_16x16x32_bf16(b[n], a[mm], acc[mq * 4 + mm][n], 0, 0, 0);
      else
        acc[mq * 4 + mm][n] = __builtin_amdgcn_mfma_f32_16x16x32_bf16(a[mm], b[n], acc[mq * 4 + mm][n], 0, 0, 0);
    }
  __builtin_amdgcn_s_setprio(0);
}

template<bool SWAP>
__device__ __forceinline__ void gemm13(const u16* __restrict__ A,
                                       const u16* __restrict__ B,
                                       f32x4 (&acc)[8][4], u16* L)
{
  const int tid = threadIdx.x, lane = tid & 63, w = tid >> 6;
  const int wr = w >> 2, wc = w & 3, lg = lane >> 4, lr = lane & 15;

#pragma unroll
  for (int m = 0; m < 8; ++m)
#pragma unroll
    for (int n = 0; n < 4; ++n) acc[m][n] = f32x4{0.f, 0.f, 0.f, 0.f};

  const u16* A1 = A + (size_t)128 * 2048;    // A half-1 rows
  const u16* B1 = B + (size_t)128 * 2048;    // B half-1 out-cols
  const int aoff = wr * 8192;                // A read base (elems)
  const int boff = 16384 + ((wc >> 1) * 8192) + ((wc & 1) * 4096);

  // prologue: tile 0 -> buf0; DRAIN (order-independent cert, r12 lesson)
  stage9(L,                 A,  0, tid);
  stage9(L + 8192,          A1, 0, tid);
  stage9(L + 16384,         B,  0, tid);
  stage9(L + 16384 + 8192,  B1, 0, tid);
  VM0();
  BARRIER();

  bf16x8 aRa[4], aRb[4], bR0[4], bR1[4];
  rd_a(aRa, L + aoff, 0, 0, lg, lr);
  rd_b(bR0, L + boff, 0, lg, lr);

#pragma unroll 1
  for (int t = 0; t < NKT - 1; ++t) {
    const u16* Lc = L + ((t & 1) << 15);
    u16* Ln = L + (((t + 1) & 1) << 15);
    // stage tile t+1 (drained at this tile's sync point)
    stage9(Ln,                A,  t + 1, tid);
    stage9(Ln + 8192,         A1, t + 1, tid);
    stage9(Ln + 16384,        B,  t + 1, tid);
    stage9(Ln + 16384 + 8192, B1, t + 1, tid);
    // compute tile t: reads + MFMAs in dependency order, no barriers —
    // compiler interleaves via fine-grained lgkmcnt (register deps).
    rd_a(aRb, Lc + aoff, 0, 1, lg, lr);          // mq1, kg0
    mmcl<SWAP>(acc, 0, aRa, bR0);                // mq0 kg0
    rd_a(aRa, Lc + aoff, 1, 0, lg, lr);          // mq0, kg1
    rd_b(bR1, Lc + boff, 1, lg, lr);             // kg1
    mmcl<SWAP>(acc, 1, aRb, bR0);                // mq1 kg0
    rd_a(aRb, Lc + aoff, 1, 1, lg, lr);          // mq1, kg1
    mmcl<SWAP>(acc, 0, aRa, bR1);                // mq0 kg1
    mmcl<SWAP>(acc, 1, aRb, bR1);                // mq1 kg1
    // single per-tile sync point
    LGKM0();
    VM0();
    BARRIER();
    // prefetch next tile's kg0 fragments (certified by the sync above)
    rd_a(aRa, Ln + aoff, 0, 0, lg, lr);
    rd_b(bR0, Ln + boff, 0, lg, lr);
  }
  {  // peeled last tile: no staging, no sync needed (register deps only)
    const u16* Lc = L + (((NKT - 1) & 1) << 15);
    rd_a(aRb, Lc + aoff, 0, 1, lg, lr);
    mmcl<SWAP>(acc, 0, aRa, bR0);
    rd_a(aRa, Lc + aoff, 1, 0, lg, lr);
    rd_b(bR1, Lc + boff, 1, lg, lr);
    mmcl<SWAP>(acc, 1, aRb, bR0);
    rd_a(aRb, Lc + aoff, 1, 1, lg, lr);
    mmcl<SWAP>(acc, 0, aRa, bR1);
    mmcl<SWAP>(acc, 1, aRb, bR1);
  }
}

// ---------------------------------------------------------------------------
// GEMM1: qkvg = x_bf16 [16384,2048] @ WTcat^T [8192,2048], +bias.
// q,g (swapped-C) -> [s][2048], 8B stores (sigmoid on g);
// k,v (normal-C)  -> directly transposed [bh][d][s], 8B stores.
// grid: 2048 blocks (64 mt x 32 nt), 16x16 supergroups for L2.
// ---------------------------------------------------------------------------
__global__ __launch_bounds__(512, 2) void k_gemm_qkvg(
    const u16* __restrict__ xb, const u16* __restrict__ WT,
    const float* __restrict__ bias,
    u16* __restrict__ q, u16* __restrict__ kT, u16* __restrict__ vT,
    u16* __restrict__ g)
{
  __shared__ u16 L[65536];
  const int bid = blockIdx.x;
  const int grp = bid >> 8, r = bid & 255;
  const int mt = ((grp & 3) << 4) + (r & 15);
  const int nt = ((grp >> 2) << 4) + (r >> 4);
  const size_t bm0 = (size_t)mt << 8;
  const int    bn0 = nt << 8;
  const int nblk = bn0 >> 11;          // 0=q 1=k 2=v 3=g
  const int ocol0 = bn0 & 2047;

  const int tid = threadIdx.x, lane = tid & 63, w = tid >> 6;
  const int wr = w >> 2, wc = w & 3, lg = lane >> 4, lr = lane & 15;

  f32x4 acc[8][4];
  const u16* Ap = xb + bm0 * NHID;
  const u16* Bp = WT + (size_t)bn0 * NHID;

  if (nblk == 0 || nblk == 3) {
    gemm13<true>(Ap, Bp, acc, L);
    u16* outp = (nblk == 0) ? q : g;
    const bool sig = (nblk == 3);
#pragma unroll
    for (int m = 0; m < 8; ++m) {
      const size_t row = bm0 + (wr << 7) + (m << 4) + lr;
#pragma unroll
      for (int n = 0; n < 4; ++n) {
        const int colb = (wc << 6) + (n << 4) + (lg << 2);
        const float* bp = bias + bn0 + colb;
        u16x4 o;
#pragma unroll
        for (int j = 0; j < 4; ++j) {
          float val = acc[m][n][j] + bp[j];
          if (sig) val = 1.f / (1.f + __expf(-val));
          o[j] = f2bf(val);
        }
        *(u16x4*)(outp + row * NHID + ocol0 + colb) = o;
      }
    }
  } else {
    gemm13<false>(Ap, Bp, acc, L);
    u16* outp = (nblk == 1) ? kT : vT;
    const int b = (int)(bm0 >> 12);
    const int srow0 = (int)(bm0 & 4095) + (wr << 7) + (lg << 2);
#pragma unroll
    for (int m = 0; m < 8; ++m) {
      const int srow = srow0 + (m << 4);
#pragma unroll
      for (int n = 0; n < 4; ++n) {
        const int cg = ocol0 + (wc << 6) + (n << 4) + lr;  // col in [0,2048)
        const int h = cg >> 7, d = cg & 127;
        const float bia = bias[bn0 + (wc << 6) + (n << 4) + lr];
        u16x4 o;
#pragma unroll
        for (int j = 0; j < 4; ++j) o[j] = f2bf(acc[m][n][j] + bia);
        *(u16x4*)(outp + (((size_t)(b * NHEAD + h) * HDIM + d) << 12) + srow) = o;
      }
    }
  }
}

// ---------------------------------------------------------------------------
// out = attn @ WoT^T + bo (fp32, swapped-C -> float4 stores)
// grid: 512 blocks (64 mt x 8 nt), 16x8 supergroups
// ---------------------------------------------------------------------------
__global__ __launch_bounds__(512, 2) void k_gemm_out(
    const u16* __restrict__ attn, const u16* __restrict__ WoT,
    const float* __restrict__ bo, float* __restrict__ out)
{
  __shared__ u16 L[65536];
  const int bid = blockIdx.x;
  const int grp = bid >> 7, rr = bid & 127;
  const int mt = (grp << 4) + (rr & 15);
  const int nt = rr >> 4;
  const size_t bm0 = (size_t)mt << 8;
  const int    bn0 = nt << 8;

  const int tid = threadIdx.x, lane = tid & 63, w = tid >> 6;
  const int wr = w >> 2, wc = w & 3, lg = lane >> 4, lr = lane & 15;

  f32x4 acc[8][4];
  gemm13<true>(attn + bm0 * NHID, WoT + (size_t)bn0 * NHID, acc, L);

#pragma unroll
  for (int m = 0; m < 8; ++m) {
    const size_t row = bm0 + (wr << 7) + (m << 4) + lr;
#pragma unroll
    for (int n = 0; n < 4; ++n) {
      const int colb = bn0 + (wc << 6) + (n << 4) + (lg << 2);
      f32x4 o;
#pragma unroll
      for (int j = 0; j < 4; ++j) o[j] = acc[m][n][j] + bo[colb + j];
      *(f32x4*)(out + row * NHID + colb) = o;
    }
  }
}

// ===========================================================================
// Small 128x128 GEMM core (round-0 verified) for the tiny per-head GEMMs
// ===========================================================================
__device__ __forceinline__ void gemm_core(const u16* A, int lda,
                                          const u16* B, int ldb,
                                          int K, f32x4 acc[4][4],
                                          u16* As, u16* Bs)
{
  const int tid  = threadIdx.x;
  const int lane = tid & 63;
  const int w    = tid >> 6;
  const int wr   = (w >> 1) << 6;
  const int wc   = (w & 1) << 6;
  const int lg   = lane >> 4;
  const int lr   = lane & 15;

#pragma unroll
  for (int m = 0; m < 4; ++m)
#pragma unroll
    for (int n = 0; n < 4; ++n) acc[m][n] = f32x4{0.f, 0.f, 0.f, 0.f};

  for (int k0 = 0; k0 < K; k0 += 32) {
#pragma unroll
    for (int issue = 0; issue < 2; ++issue) {
      int c   = issue * 256 + tid;
      int row = c >> 2, cc = (c & 3) << 3;
      async_copy16(As + c * 8, A + (size_t)row * lda + k0 + cc);
    }
#pragma unroll
    for (int issue = 0; issue < 2; ++issue) {
      int c   = issue * 256 + tid;
      int row = c >> 2, cc = (c & 3) << 3;
      async_copy16(Bs + c * 8, B + (size_t)row * ldb + k0 + cc);
    }
    __syncthreads();

    bf16x8 af[4], bv[4];
#pragma unroll
    for (int m = 0; m < 4; ++m)
      af[m] = *(const bf16x8*)(As + ((wr + m * 16 + lr) << 5) + (lg << 3));
#pragma unroll
    for (int n = 0; n < 4; ++n)
      bv[n] = *(const bf16x8*)(Bs + ((wc + n * 16 + lr) << 5) + (lg << 3));

#pragma unroll
    for (int m = 0; m < 4; ++m)
#pragma unroll
      for (int n = 0; n < 4; ++n)
        acc[m][n] = __builtin_amdgcn_mfma_f32_16x16x32_bf16(af[m], bv[n], acc[m][n], 0, 0, 0);

    __syncthreads();
  }
}

// ---------------------------------------------------------------------------
// kv partial: C[e][d] = sum_{s chunk} vT[e][s]*kT[d][s]; grid (64 bh, 8 split)
// ---------------------------------------------------------------------------
__global__ __launch_bounds__(256) void k_gemm_kv(
    const u16* __restrict__ vT, const u16* __restrict__ kT, float* __restrict__ part)
{
  __shared__ u16 As[128 * 32];
  __shared__ u16 Bs[128 * 32];
  const int bh = blockIdx.x, sp = blockIdx.y;
  const u16* A  = vT + (size_t)bh * (HDIM * NS) + sp * 512;
  const u16* Bt = kT + (size_t)bh * (HDIM * NS) + sp * 512;
  f32x4 acc[4][4];
  gemm_core(A, NS, Bt, NS, 512, acc, As, Bs);

  float* outp = part + ((size_t)sp * 64 + bh) * 16384;
  const int tid = threadIdx.x, lane = tid & 63, w = tid >> 6;
  const int wr = (w >> 1) << 6, wc = (w & 1) << 6, lg = lane >> 4, lr = lane & 15;
#pragma unroll
  for (int m = 0; m < 4; ++m)
#pragma unroll
    for (int n = 0; n < 4; ++n) {
      const int col = wc + n * 16 + lr;
#pragma unroll
      for (int j = 0; j < 4; ++j) {
        const int row = wr + m * 16 + lg * 4 + j;
        outp[row * 128 + col] = acc[m][n][j];
      }
    }
}

// ---------------------------------------------------------------------------
// attn = (q @ kv) * g ; grid (32 stiles, 64 bh)
// ---------------------------------------------------------------------------
__global__ __launch_bounds__(256) void k_gemm_attn(
    const u16* __restrict__ q, const u16* __restrict__ kvT,
    const u16* __restrict__ g, u16* __restrict__ attn)
{
  __shared__ u16 As[128 * 32];
  __shared__ u16 Bs[128 * 32];
  const int st = blockIdx.x, bh = blockIdx.y;
  const int b = bh >> 4, h = bh & 15;
  const size_t bs0 = (size_t)b * NS + st * 128;
  f32x4 acc[4][4];
  gemm_core(q + bs0 * NHID + h * HDIM, NHID, kvT + (size_t)bh * 16384, HDIM, HDIM, acc, As, Bs);

  const int tid = threadIdx.x, lane = tid & 63, w = tid >> 6;
  const int wr = (w >> 1) << 6, wc = (w & 1) << 6, lg = lane >> 4, lr = lane & 15;
#pragma unroll
  for (int m = 0; m < 4; ++m)
#pragma unroll
    for (int n = 0; n < 4; ++n) {
      const int col = wc + n * 16 + lr;
#pragma unroll
      for (int j = 0; j < 4; ++j) {
        const int row = wr + m * 16 + lg * 4 + j;
        const size_t idx = (bs0 + row) * NHID + h * HDIM + col;
        attn[idx] = f2bf(acc[m][n][j] * bf2f(g[idx]));
      }
    }
}

// ---------------------------------------------------------------------------
// x fp32 -> bf16
// ---------------------------------------------------------------------------
__global__ __launch_bounds__(256) void k_cvt_x(const float* __restrict__ x, u16* __restrict__ xb)
{
  const size_t i = (size_t)blockIdx.x * 256 + threadIdx.x;
  const float4* xf = (const float4*)x;
  float4 a = xf[2 * i];
  float4 b = xf[2 * i + 1];
  u16x8 o;
  o[0] = f2bf(a.x); o[1] = f2bf(a.y); o[2] = f2bf(a.z); o[3] = f2bf(a.w);
  o[4] = f2bf(b.x); o[5] = f2bf(b.y); o[6] = f2bf(b.z); o[7] = f2bf(b.w);
  ((u16x8*)xb)[i] = o;
}

// ---------------------------------------------------------------------------
// All 5 weights [2048][2048] fp32 -> WT bf16 transposed, one launch.
// grid (32 ktiles, 32 ntiles, 5 weights)
// ---------------------------------------------------------------------------
__global__ __launch_bounds__(256) void k_cvt_w_t5(
    const float* __restrict__ Wq, const float* __restrict__ Wk,
    const float* __restrict__ Wv, const float* __restrict__ Wg,
    const float* __restrict__ Wo,
    u16* __restrict__ WT, u16* __restrict__ WoT)
{
  __shared__ u16 t[64][72];
  const int kt = blockIdx.x, nt = blockIdx.y, z = blockIdx.z;
  const float* W = (z == 0) ? Wq : (z == 1) ? Wk : (z == 2) ? Wv
                 : (z == 3) ? Wg : Wo;
  u16* dst = (z == 4) ? WoT : (WT + (size_t)z * 2048 * 2048);
  const int tid = threadIdx.x;
#pragma unroll
  for (int pass = 0; pass < 4; ++pass) {
    int c = pass * 256 + tid;
    int r = c >> 4, cc = (c & 15) << 2;
    float4 vv = *(const float4*)(W + (size_t)(kt * 64 + r) * 2048 + nt * 64 + cc);
    u16x4 o;
    o[0] = f2bf(vv.x); o[1] = f2bf(vv.y); o[2] = f2bf(vv.z); o[3] = f2bf(vv.w);
    *(u16x4*)&t[r][cc] = o;
  }
  __syncthreads();
#pragma unroll
  for (int pass = 0; pass < 2; ++pass) {
    int c = pass * 256 + tid;
    int rn = c >> 3, cs = (c & 7) << 3;
    u16x8 o;
#pragma unroll
    for (int j = 0; j < 8; ++j) o[j] = t[cs + j][rn];
    *(u16x8*)(dst + (size_t)(nt * 64 + rn) * 2048 + kt * 64 + cs) = o;
  }
}

// ---------------------------------------------------------------------------
__global__ __launch_bounds__(256) void k_bias_cat(
    const float* __restrict__ bq, const float* __restrict__ bk,
    const float* __restrict__ bv, const float* __restrict__ bg, float* __restrict__ o)
{
  const int i = blockIdx.x * 256 + threadIdx.x;  // 8192
  const int blk = i >> 11;
  const float* s = (blk == 0) ? bq : (blk == 1) ? bk : (blk == 2) ? bv : bg;
  o[i] = s[i & 2047];
}

__global__ __launch_bounds__(256) void k_kv_reduce(const float* __restrict__ part, u16* __restrict__ kvT)
{
  const int i = blockIdx.x * 256 + threadIdx.x;  // 1,048,576
  float s = 0.f;
#pragma unroll
  for (int sp = 0; sp < 8; ++sp) s += part[(size_t)sp * 1048576 + i];
  kvT[i] = f2bf(s);
}

// ---------------------------------------------------------------------------
extern "C" void kernel_launch(void* const* d_in, const int* in_sizes, int n_in,
                              void* d_out, int out_size, void* d_ws, size_t ws_size,
                              hipStream_t stream)
{
  const float* x  = (const float*)d_in[0];
  const float* Wq = (const float*)d_in[1];
  const float* bq = (const float*)d_in[2];
  const float* Wk = (const float*)d_in[3];
  const float* bk = (const float*)d_in[4];
  const float* Wv = (const float*)d_in[5];
  const float* bv = (const float*)d_in[6];
  const float* Wg = (const float*)d_in[7];
  const float* bg = (const float*)d_in[8];
  const float* Wo = (const float*)d_in[9];
  const float* bo = (const float*)d_in[10];
  float* out = (float*)d_out;

  char* ws = (char*)d_ws;
  u16*   xb   = (u16*)(ws + 0x00000000ULL);  // 64MB
  u16*   WT   = (u16*)(ws + 0x04000000ULL);  // 32MB  [Wq|Wk|Wv|Wg]^T bf16
  u16*   WoT  = (u16*)(ws + 0x06000000ULL);  // 8MB
  float* bias = (float*)(ws + 0x06800000ULL);// 32KB
  u16*   q    = (u16*)(ws + 0x06900000ULL);  // 64MB
  u16*   kT   = (u16*)(ws + 0x0A900000ULL);  // 64MB  [bh][d][s]
  u16*   vT   = (u16*)(ws + 0x0E900000ULL);  // 64MB  [bh][d][s]
  u16*   gg   = (u16*)(ws + 0x12900000ULL);  // 64MB
  u16*   kvT  = (u16*)(ws + 0x16900000ULL);  // 2MB
  // aliases (producer/consumer disjoint across sequential launches)
  float* part = (float*)WT;   // WT dead after qkvg (exactly 32MB)
  u16*   attn = xb;           // xb dead after qkvg

  if (ws_size < 0x16B00000ULL) return;

  k_cvt_x<<<16384, 256, 0, stream>>>(x, xb);
  k_cvt_w_t5<<<dim3(32, 32, 5), 256, 0, stream>>>(Wq, Wk, Wv, Wg, Wo, WT, WoT);
  k_bias_cat<<<32, 256, 0, stream>>>(bq, bk, bv, bg, bias);

  k_gemm_qkvg<<<2048, 512, 0, stream>>>(xb, WT, bias, q, kT, vT, gg);

  k_gemm_kv<<<dim3(64, 8), 256, 0, stream>>>(vT, kT, part);
  k_kv_reduce<<<4096, 256, 0, stream>>>(part, kvT);

  k_gemm_attn<<<dim3(32, 64), 256, 0, stream>>>(q, kvT, gg, attn);
  k_gemm_out<<<512, 512, 0, stream>>>(attn, WoT, bo, out);
}